// Round 11
// baseline (608.083 us; speedup 1.0000x reference)
//
#include <hip/hip_runtime.h>
#include <hip/hip_fp16.h>

// ---------------------------------------------------------------------------
// GATNet forward: 3x (GATConv -> ReLU -> BN) -> mean-pool -> MLP(128->64->1)
// N=100000, E=1.6M (+N self loops), HID=128, H=4, D=32, G=128.
// R10: GEMM operand-swapped (computes h^T fragments -> each lane owns 4
// consecutive cols of one row): h epilogue = 16x8B packed stores (was 64x2B
// scalar), scores = one float4 store. X prefetch dropped + launch_bounds
// (256,4) to cap VGPR<=128 -> 4 waves/SIMD (was ~2). Aggregate (fp16
// payload) at ~85% of copy ceiling, unchanged.
// ---------------------------------------------------------------------------

typedef __bf16 bf16x8 __attribute__((ext_vector_type(8)));
typedef float  f32x4  __attribute__((ext_vector_type(4)));
typedef unsigned int u32x4 __attribute__((ext_vector_type(4)));

#define BCOLS 144   // 128 h cols + 4 wa_src + 4 wa_dst + 8 zero pad
#define BSTRIDE (BCOLS * 128)

#define MAXBKT 800  // >= ceil(Nn/128); Nn=100000 -> 782
#define BCAP   4096 // bucket capacity; mean 2176

// Pass 1: bucket edges by dst>>7 into block-exclusive runs; zero gsum/gcnt.
__global__ __launch_bounds__(256)
void k_bucket(const int* __restrict__ ei, unsigned int* __restrict__ bkt,
              int* __restrict__ bcnt, float* __restrict__ gsum,
              int* __restrict__ gcnt, int Ne, int Nn, int nbkt, int Gg) {
    __shared__ int lcnt[MAXBKT];
    __shared__ int lbase[MAXBKT];
    int tid = threadIdx.x;
    int gid = blockIdx.x * 256 + tid;
    if (gid < Gg * 128) gsum[gid] = 0.f;
    if (gid < Gg) gcnt[gid] = 0;
    for (int i = tid; i < nbkt; i += 256) lcnt[i] = 0;
    __syncthreads();
    int chunk0 = blockIdx.x * 2048;
    int nnz = Ne + Nn;
    for (int i = 0; i < 8; ++i) {
        int e = chunk0 + i * 256 + tid;
        if (e < nnz) {
            int d = (e < Ne) ? ei[Ne + e] : (e - Ne);
            atomicAdd(&lcnt[d >> 7], 1);
        }
    }
    __syncthreads();
    for (int b = tid; b < nbkt; b += 256) {
        int c = lcnt[b];
        lbase[b] = (c > 0) ? atomicAdd(&bcnt[b], c) : 0;
        lcnt[b] = 0;
    }
    __syncthreads();
    for (int i = 0; i < 8; ++i) {
        int e = chunk0 + i * 256 + tid;
        if (e < nnz) {
            int s, d;
            if (e < Ne) { s = ei[e]; d = ei[Ne + e]; }
            else        { s = e - Ne; d = e - Ne; }
            int b = d >> 7;
            int r = atomicAdd(&lcnt[b], 1);
            bkt[(long)b * BCAP + lbase[b] + r] = ((unsigned)s << 7) | (unsigned)(d & 127);
        }
    }
}

// One-block exclusive scan of the nbkt bucket counts.
__global__ __launch_bounds__(1024)
void k_bktscan(const int* __restrict__ bcnt, int* __restrict__ bktbase, int nbkt) {
    __shared__ int s0[1024], s1[1024];
    int t = threadIdx.x;
    int v = (t < nbkt) ? bcnt[t] : 0;
    s0[t] = v;
    __syncthreads();
    int* src = s0; int* dst = s1;
    for (int off = 1; off < 1024; off <<= 1) {
        int x = src[t];
        if (t >= off) x += src[t - off];
        dst[t] = x;
        __syncthreads();
        int* tw = src; src = dst; dst = tw;
    }
    if (t < nbkt) bktbase[t] = src[t] - v;   // exclusive
}

// Per-bucket: LDS hist -> LDS scan -> coalesced rowptr write -> scatter col.
__global__ __launch_bounds__(256)
void k_bscatter2(const unsigned int* __restrict__ bkt, const int* __restrict__ bcnt,
                 const int* __restrict__ bktbase, int* __restrict__ rowptr,
                 int* __restrict__ colv, int Nn, int nnz) {
    __shared__ int h[128], sc0[128], sc1[128];
    int b = blockIdx.x;
    int tid = threadIdx.x;
    if (tid < 128) h[tid] = 0;
    __syncthreads();
    int cnt = bcnt[b];
    int base = bktbase[b];
    const unsigned int* bp = bkt + (long)b * BCAP;
    for (int i = tid; i < cnt; i += 256) atomicAdd(&h[bp[i] & 127], 1);
    __syncthreads();
    if (tid < 128) sc0[tid] = h[tid];
    __syncthreads();
    int* src = sc0; int* dst = sc1;
    for (int off = 1; off < 128; off <<= 1) {
        if (tid < 128) {
            int x = src[tid];
            if (tid >= off) x += src[tid - off];
            dst[tid] = x;
        }
        __syncthreads();
        int* tw = src; src = dst; dst = tw;
    }
    int node = b * 128 + tid;
    if (tid < 128) {
        int excl = src[tid] - h[tid];
        int st = base + excl;
        h[tid] = st;                       // reuse as cursor
        if (node < Nn) rowptr[node] = st;
    }
    if (b == 0 && tid == 0) rowptr[Nn] = nnz;
    __syncthreads();
    for (int i = tid; i < cnt; i += 256) {
        unsigned int e = bp[i];
        int pos = atomicAdd(&h[e & 127], 1);
        colv[pos] = (int)(e >> 7);
    }
}

// merged prep: BN fold; W transpose/split bf16 hi/lo [l][col][k] cols 0..127;
// wa = W·att -> cols 128..135; zero pad 136..143.
__global__ void k_prep(const float* __restrict__ gamma, const float* __restrict__ beta,
                       const float* __restrict__ mean, const float* __restrict__ var,
                       float* __restrict__ bn_mul, float* __restrict__ bn_add,
                       const float* __restrict__ W, const float* __restrict__ asrc,
                       const float* __restrict__ adst,
                       __bf16* __restrict__ Hi, __bf16* __restrict__ Lo) {
    int gid = blockIdx.x * 256 + threadIdx.x;
    if (gid < 384) {
        float sc = gamma[gid] / sqrtf(var[gid] + 1e-5f);
        bn_mul[gid] = sc;
        bn_add[gid] = beta[gid] - mean[gid] * sc;
    }
    if (gid < 3 * 128 * 128) {
        int l = gid >> 14;
        int k = (gid >> 7) & 127;
        int n = gid & 127;
        float f = W[gid];
        __bf16 h = (__bf16)f;
        int o = l * BSTRIDE + n * 128 + k;
        Hi[o] = h;
        Lo[o] = (__bf16)(f - (float)h);
    }
    if (gid < 3 * 128 * 8) {            // wa projections
        int l = gid >> 10;
        int r = gid & 1023;
        int k = r >> 3;
        int j = r & 7;                  // 0..3 src head, 4..7 dst head
        int hh = j & 3;
        const float* av = (j < 4 ? asrc : adst) + l * 128 + hh * 32;
        const float* wp = W + l * 16384 + k * 128 + hh * 32;
        float sum = 0.f;
#pragma unroll
        for (int d = 0; d < 32; ++d) sum = fmaf(wp[d], av[d], sum);
        __bf16 h = (__bf16)sum;
        int o = l * BSTRIDE + (128 + j) * 128 + k;
        Hi[o] = h;
        Lo[o] = (__bf16)(sum - (float)h);
    }
    if (gid < 3 * 128 * 8) {            // zero pad cols 136..143
        int l = gid >> 10;
        int r = gid & 1023;
        int k = r >> 3;
        int j = r & 7;
        int o = l * BSTRIDE + (136 + j) * 128 + k;
        Hi[o] = (__bf16)0.f;
        Lo[o] = (__bf16)0.f;
    }
}

// MFMA GEMM over extended B (144 cols), OPERAND-SWAPPED: computes h^T
// fragments (D' = W^T·X^T). Lane li owns row r = rowBase + rt*16 + li; per
// col-tile ct it holds 4 consecutive cols 16ct+4b..+3 -> 8B packed stores.
// Score tile (ct=8): b=0 -> as_[4r..] float4, b=1 -> ad_, b=2/3 pad.
__global__ __launch_bounds__(256, 4)
void k_gemm_mfma(const float* __restrict__ X, const __bf16* __restrict__ BtHi,
                 const __bf16* __restrict__ BtLo, __half* __restrict__ Hout,
                 float* __restrict__ as_, float* __restrict__ ad_, int Nn) {
    int t = threadIdx.x;
    int w = t >> 6;
    int lane = t & 63;
    int li = lane & 15;
    int b  = lane >> 4;          // 0..3
    long rowBase = (long)blockIdx.x * 128 + w * 32;

    f32x4 acc[2][9];
#pragma unroll
    for (int rt = 0; rt < 2; ++rt)
#pragma unroll
        for (int ct = 0; ct < 9; ++ct) acc[rt][ct] = (f32x4){0.f, 0.f, 0.f, 0.f};

    long rA[2];
#pragma unroll
    for (int rt = 0; rt < 2; ++rt) {
        long r = rowBase + rt * 16 + li;
        rA[rt] = (r > Nn - 1) ? (Nn - 1) : r;
    }

#pragma unroll
    for (int ks = 0; ks < 4; ++ks) {
        int k0 = ks * 32 + 8 * b;
        bf16x8 ahi[2], alo[2];
#pragma unroll
        for (int rt = 0; rt < 2; ++rt) {
            const float* xp = X + rA[rt] * 128 + k0;
            float4 f0 = *(const float4*)xp;
            float4 f1 = *(const float4*)(xp + 4);
            float af[8] = {f0.x, f0.y, f0.z, f0.w, f1.x, f1.y, f1.z, f1.w};
#pragma unroll
            for (int j = 0; j < 8; ++j) {
                __bf16 h = (__bf16)af[j];
                ahi[rt][j] = h;
                alo[rt][j] = (__bf16)(af[j] - (float)h);
            }
        }
#pragma unroll
        for (int ct = 0; ct < 9; ++ct) {
            int coff = (ct * 16 + li) * 128 + k0;
            bf16x8 bhi = *(const bf16x8*)(BtHi + coff);
            bf16x8 blo = *(const bf16x8*)(BtLo + coff);
#pragma unroll
            for (int rt = 0; rt < 2; ++rt) {
                // swapped operands: D' = W^T · X^T  (3-term bf16 split)
                acc[rt][ct] = __builtin_amdgcn_mfma_f32_16x16x32_bf16(bhi, ahi[rt], acc[rt][ct], 0, 0, 0);
                acc[rt][ct] = __builtin_amdgcn_mfma_f32_16x16x32_bf16(bhi, alo[rt], acc[rt][ct], 0, 0, 0);
                acc[rt][ct] = __builtin_amdgcn_mfma_f32_16x16x32_bf16(blo, ahi[rt], acc[rt][ct], 0, 0, 0);
            }
        }
    }

    // ---- store h (fp16, 8B packed) + attention scores (float4) ----
#pragma unroll
    for (int rt = 0; rt < 2; ++rt) {
        long r = rowBase + rt * 16 + li;
        if (r < Nn) {
            __half* op = Hout + r * 128 + 4 * b;
#pragma unroll
            for (int ct = 0; ct < 8; ++ct) {
                union { __half2 h2[2]; uint2 u; } pk;
                pk.h2[0] = __floats2half2_rn(acc[rt][ct][0], acc[rt][ct][1]);
                pk.h2[1] = __floats2half2_rn(acc[rt][ct][2], acc[rt][ct][3]);
                *(uint2*)(op + ct * 16) = pk.u;
            }
            if (b == 0)
                *(float4*)(as_ + 4 * r) = make_float4(acc[rt][8][0], acc[rt][8][1],
                                                      acc[rt][8][2], acc[rt][8][3]);
            else if (b == 1)
                *(float4*)(ad_ + 4 * r) = make_float4(acc[rt][8][0], acc[rt][8][1],
                                                      acc[rt][8][2], acc[rt][8][3]);
        }
    }
}

#define LEAKY(x) ((x) > 0.f ? (x) : 0.2f * (x))

// One wave per dst node, 4 nodes/block. h rows are fp16 (256 B); lane li owns
// 8 cols = 16 B per edge; 8 edges/iter. fp32 accumulate.
__global__ __launch_bounds__(256)
void k_aggregate(const __half* __restrict__ Hb, const float* __restrict__ as_,
                 const float* __restrict__ ad_, const int* __restrict__ rowptr,
                 const int* __restrict__ col, const float* __restrict__ bias,
                 const float* __restrict__ bn_mul, const float* __restrict__ bn_add,
                 float* __restrict__ Xout, int Nn) {
    __shared__ float s_alpha[4][64][4];
    __shared__ int   s_off[4][64];
    int w = threadIdx.x >> 6;
    int n = (blockIdx.x << 2) + w;
    if (n >= Nn) return;
    int lane = threadIdx.x & 63;
    int start = rowptr[n], end = rowptr[n + 1];
    int deg = end - start;

    if (deg <= 64) {
        // ---- phase A: lane=(slot,head), one-shot softmax ----
        int hh = lane & 3;
        int slot = lane >> 2;
        float adn = ad_[4 * n + hh];
        float esc[4]; int scl[4];
#pragma unroll
        for (int c = 0; c < 4; ++c) {
            int eidx = (c << 4) + slot;
            float e = -1e30f; int s = 0;
            if (eidx < deg) {
                s = col[start + eidx];
                e = LEAKY(as_[4 * s + hh] + adn);
            }
            esc[c] = e; scl[c] = s;
        }
        float m = fmaxf(fmaxf(esc[0], esc[1]), fmaxf(esc[2], esc[3]));
#pragma unroll
        for (int msk = 4; msk < 64; msk <<= 1) m = fmaxf(m, __shfl_xor(m, msk, 64));
        float p[4];
        float den = 0.f;
#pragma unroll
        for (int c = 0; c < 4; ++c) { p[c] = __expf(esc[c] - m); den += p[c]; }
#pragma unroll
        for (int msk = 4; msk < 64; msk <<= 1) den += __shfl_xor(den, msk, 64);
        float inv = 1.f / (den + 1e-16f);
#pragma unroll
        for (int c = 0; c < 4; ++c)
            s_alpha[w][(c << 4) + slot][hh] = p[c] * inv;
        if (hh == 0) {
#pragma unroll
            for (int c = 0; c < 4; ++c)
                s_off[w][(c << 4) + slot] = scl[c] << 8;   // byte offset (fp16 row)
        }

        // ---- phase B: 8 edges per iter (2 x 4 quarters), 16B/lane ----
        int quarter = lane >> 4;
        int li = lane & 15;
        int hB = li >> 2;
        int cByte = li << 4;                 // 16 B = 8 halves
        const char* hb8 = (const char*)Hb;
        float accA[8], accB[8];
#pragma unroll
        for (int i = 0; i < 8; ++i) { accA[i] = 0.f; accB[i] = 0.f; }
        int degU = (deg + 7) & ~7;
        for (int j = 0; j < degU; j += 8) {
            int e0 = j + quarter;
            int e1 = j + 4 + quarter;
            int off0 = s_off[w][e0];
            int off1 = s_off[w][e1];
            float al0 = s_alpha[w][e0][hB];
            float al1 = s_alpha[w][e1][hB];
            u32x4 r0 = *(const u32x4*)(hb8 + off0 + cByte);
            u32x4 r1 = *(const u32x4*)(hb8 + off1 + cByte);
            const __half2* h0 = (const __half2*)&r0;
            const __half2* h1 = (const __half2*)&r1;
#pragma unroll
            for (int q = 0; q < 4; ++q) {
                float2 f0 = __half22float2(h0[q]);
                float2 f1 = __half22float2(h1[q]);
                accA[2 * q]     = fmaf(f0.x, al0, accA[2 * q]);
                accA[2 * q + 1] = fmaf(f0.y, al0, accA[2 * q + 1]);
                accB[2 * q]     = fmaf(f1.x, al1, accB[2 * q]);
                accB[2 * q + 1] = fmaf(f1.y, al1, accB[2 * q + 1]);
            }
        }
        float acc[8];
#pragma unroll
        for (int i = 0; i < 8; ++i) {
            float v = accA[i] + accB[i];
            v += __shfl_xor(v, 16, 64);
            v += __shfl_xor(v, 32, 64);
            acc[i] = v;
        }
        if (lane < 16) {
            int c0 = li << 3;
            float4 bz0 = *(const float4*)(bias + c0);
            float4 bz1 = *(const float4*)(bias + c0 + 4);
            float4 m0 = *(const float4*)(bn_mul + c0);
            float4 m1 = *(const float4*)(bn_mul + c0 + 4);
            float4 a0 = *(const float4*)(bn_add + c0);
            float4 a1 = *(const float4*)(bn_add + c0 + 4);
            float4 o0, o1;
            o0.x = fmaf(fmaxf(acc[0] + bz0.x, 0.f), m0.x, a0.x);
            o0.y = fmaf(fmaxf(acc[1] + bz0.y, 0.f), m0.y, a0.y);
            o0.z = fmaf(fmaxf(acc[2] + bz0.z, 0.f), m0.z, a0.z);
            o0.w = fmaf(fmaxf(acc[3] + bz0.w, 0.f), m0.w, a0.w);
            o1.x = fmaf(fmaxf(acc[4] + bz1.x, 0.f), m1.x, a1.x);
            o1.y = fmaf(fmaxf(acc[5] + bz1.y, 0.f), m1.y, a1.y);
            o1.z = fmaf(fmaxf(acc[6] + bz1.z, 0.f), m1.z, a1.z);
            o1.w = fmaf(fmaxf(acc[7] + bz1.w, 0.f), m1.w, a1.w);
            *(float4*)(Xout + (long)n * 128 + c0)     = o0;
            *(float4*)(Xout + (long)n * 128 + c0 + 4) = o1;
        }
        return;
    }

    // ---- fallback (deg > 64): 3-pass ----
    int hh = lane & 3;
    float adn = ad_[n * 4 + hh];
    float m = -1e30f;
    for (int base = start; base < end; base += 16) {
        int idx = base + (lane >> 2);
        float sc = -1e30f;
        if (idx < end) {
            int s = col[idx];
            float e = as_[s * 4 + hh] + adn;
            sc = LEAKY(e);
        }
        m = fmaxf(m, sc);
    }
    for (int msk = 4; msk < 64; msk <<= 1) m = fmaxf(m, __shfl_xor(m, msk, 64));
    float den = 0.f;
    for (int base = start; base < end; base += 16) {
        int idx = base + (lane >> 2);
        if (idx < end) {
            int s = col[idx];
            float e = as_[s * 4 + hh] + adn;
            e = LEAKY(e);
            den += __expf(e - m);
        }
    }
    for (int msk = 4; msk < 64; msk <<= 1) den += __shfl_xor(den, msk, 64);
    int hB = lane >> 4;
    float mB   = __shfl(m, hB, 64);
    float invB = 1.f / (__shfl(den, hB, 64) + 1e-16f);
    float adB  = ad_[n * 4 + hB];
    int c0 = lane << 1;
    float acc0 = 0.f, acc1 = 0.f;
    for (int i = start; i < end; ++i) {
        int s = col[i];
        float e = as_[s * 4 + hB] + adB;
        e = LEAKY(e);
        float alpha = __expf(e - mB) * invB;
        float2 hv = __half22float2(*(const __half2*)(Hb + (long)s * 128 + c0));
        acc0 = fmaf(hv.x, alpha, acc0);
        acc1 = fmaf(hv.y, alpha, acc1);
    }
    float v0 = acc0 + bias[c0], v1 = acc1 + bias[c0 + 1];
    v0 = fmaxf(v0, 0.f); v1 = fmaxf(v1, 0.f);
    v0 = fmaf(v0, bn_mul[c0], bn_add[c0]);
    v1 = fmaf(v1, bn_mul[c0 + 1], bn_add[c0 + 1]);
    *(float2*)(Xout + (long)n * 128 + c0) = make_float2(v0, v1);
}

__global__ __launch_bounds__(128)
void k_pool(const float* __restrict__ X, const int* __restrict__ batch,
            float* __restrict__ gsum, int* __restrict__ gcnt, int Nn) {
    int c = threadIdx.x;
    int n0 = blockIdx.x * 64;
    if (n0 >= Nn) return;
    int nend = (n0 + 64 < Nn) ? n0 + 64 : Nn;
    float local = 0.f;
    int gcur = batch[n0];
    int cnt = 0;
    for (int n = n0; n < nend; ++n) {
        int g = batch[n];
        if (g != gcur) {
            atomicAdd(&gsum[gcur * 128 + c], local);
            if (c == 0) atomicAdd(&gcnt[gcur], cnt);
            local = 0.f; cnt = 0; gcur = g;
        }
        local += X[(long)n * 128 + c];
        cnt += 1;
    }
    atomicAdd(&gsum[gcur * 128 + c], local);
    if (c == 0) atomicAdd(&gcnt[gcur], cnt);
}

__global__ __launch_bounds__(64)
void k_head(const float* __restrict__ gsum, const int* __restrict__ gcnt,
            const float* __restrict__ Wh1, const float* __restrict__ bh1,
            const float* __restrict__ Wh2, const float* __restrict__ bh2,
            float* __restrict__ outp) {
    __shared__ float pooled[128];
    int g = blockIdx.x;
    int j = threadIdx.x;
    int cnt = gcnt[g];
    float inv = 1.f / (float)(cnt > 1 ? cnt : 1);
    pooled[j]      = gsum[g * 128 + j] * inv;
    pooled[j + 64] = gsum[g * 128 + 64 + j] * inv;
    __syncthreads();
    float acc = bh1[j];
    for (int k = 0; k < 128; ++k) acc = fmaf(pooled[k], Wh1[k * 64 + j], acc);
    acc = fmaxf(acc, 0.f);
    float prod = acc * Wh2[j];
    for (int msk = 1; msk < 64; msk <<= 1) prod += __shfl_xor(prod, msk, 64);
    if (j == 0) outp[g] = prod + bh2[0];
}

extern "C" void kernel_launch(void* const* d_in, const int* in_sizes, int n_in,
                              void* d_out, int out_size, void* d_ws, size_t ws_size,
                              hipStream_t stream) {
    const float* x       = (const float*)d_in[0];
    const int*   ei      = (const int*)d_in[1];
    const int*   batch   = (const int*)d_in[2];
    const float* W       = (const float*)d_in[3];
    const float* att_src = (const float*)d_in[4];
    const float* att_dst = (const float*)d_in[5];
    const float* bias    = (const float*)d_in[6];
    const float* gamma   = (const float*)d_in[7];
    const float* beta    = (const float*)d_in[8];
    const float* bn_mean = (const float*)d_in[9];
    const float* bn_var  = (const float*)d_in[10];
    const float* Wh1     = (const float*)d_in[11];
    const float* bh1     = (const float*)d_in[12];
    const float* Wh2     = (const float*)d_in[13];
    const float* bh2     = (const float*)d_in[14];
    float* out = (float*)d_out;

    const int Nn = in_sizes[0] / 128;
    const int Ne = in_sizes[1] / 2;
    const int Gg = out_size;
    const int nnz = Ne + Nn;
    const int nbkt = (Nn + 127) / 128;

    char* ws = (char*)d_ws;
    size_t off = 0;
    auto alloc = [&](size_t bytes) -> char* {
        char* p = ws + off;
        off = (off + bytes + 255) & ~(size_t)255;
        return p;
    };
    float*        bufA    = (float*)alloc((size_t)Nn * 128 * 4);
    __half*       bufH    = (__half*)alloc((size_t)Nn * 128 * 2);
    float*        as_     = (float*)alloc((size_t)Nn * 4 * 4);
    float*        ad_     = (float*)alloc((size_t)Nn * 4 * 4);
    int*          rowptr  = (int*)alloc((size_t)(Nn + 1) * 4);
    int*          col     = (int*)alloc((size_t)nnz * 4);
    float*        bn_mul  = (float*)alloc(384 * 4);
    float*        bn_add  = (float*)alloc(384 * 4);
    float*        gsum    = (float*)alloc((size_t)Gg * 128 * 4);
    int*          gcnt    = (int*)alloc((size_t)Gg * 4);
    __bf16*       WtHi    = (__bf16*)alloc((size_t)3 * BSTRIDE * 2);
    __bf16*       WtLo    = (__bf16*)alloc((size_t)3 * BSTRIDE * 2);
    unsigned int* bkt     = (unsigned int*)alloc((size_t)nbkt * BCAP * 4);
    int*          bcnt    = (int*)alloc((size_t)nbkt * 4);
    int*          bktbase = (int*)alloc((size_t)nbkt * 4);

    // ---- CSR build (consolidated) + param prep ----
    hipMemsetAsync(bcnt, 0, (size_t)nbkt * 4, stream);
    k_prep<<<192, 256, 0, stream>>>(gamma, beta, bn_mean, bn_var, bn_mul, bn_add,
                                    W, att_src, att_dst, WtHi, WtLo);
    k_bucket<<<(nnz + 2047) / 2048, 256, 0, stream>>>(ei, bkt, bcnt, gsum, gcnt,
                                                      Ne, Nn, nbkt, Gg);
    k_bktscan<<<1, 1024, 0, stream>>>(bcnt, bktbase, nbkt);
    k_bscatter2<<<nbkt, 256, 0, stream>>>(bkt, bcnt, bktbase, rowptr, col, Nn, nnz);

    // ---- 3 GAT layers ----
    const float* cur = x;
    for (int l = 0; l < 3; ++l) {
        k_gemm_mfma<<<(Nn + 127) / 128, 256, 0, stream>>>(cur, WtHi + l * BSTRIDE,
                                                          WtLo + l * BSTRIDE,
                                                          bufH, as_, ad_, Nn);
        k_aggregate<<<(Nn + 3) / 4, 256, 0, stream>>>(bufH, as_, ad_, rowptr, col,
                                                      bias + l * 128, bn_mul + l * 128,
                                                      bn_add + l * 128, bufA, Nn);
        cur = bufA;
    }

    // ---- pool + head ----
    k_pool<<<(Nn + 63) / 64, 128, 0, stream>>>(bufA, batch, gsum, gcnt, Nn);
    k_head<<<Gg, 64, 0, stream>>>(gsum, gcnt, Wh1, bh1, Wh2, bh2, out);
}

// Round 12
// 527.052 us; speedup vs baseline: 1.1537x; 1.1537x over previous
//
#include <hip/hip_runtime.h>
#include <hip/hip_fp16.h>

// ---------------------------------------------------------------------------
// GATNet forward: 3x (GATConv -> ReLU -> BN) -> mean-pool -> MLP(128->64->1)
// N=100000, E=1.6M (+N self loops), HID=128, H=4, D=32, G=128.
// R11: GEMM v3 — W (bf16 hi/lo, 144 cols) staged in LDS once per block per
// K-slice, pre-arranged in fragment order (tile=1KB at lane*16 -> stride-1
// ds_write/read_b128, conflict-free). Cuts B L2 traffic 4x and per-wave
// register footprint (no launch_bounds min-wave bound — R10's (256,4) caused
// spills, +34us). Swapped-operand epilogue kept (packed 8B h stores).
// ---------------------------------------------------------------------------

typedef __bf16 bf16x8 __attribute__((ext_vector_type(8)));
typedef float  f32x4  __attribute__((ext_vector_type(4)));
typedef unsigned int u32x4 __attribute__((ext_vector_type(4)));

#define BCOLS 144   // 128 h cols + 4 wa_src + 4 wa_dst + 8 zero pad
#define BSTRIDE (BCOLS * 128)

#define MAXBKT 800  // >= ceil(Nn/128); Nn=100000 -> 782
#define BCAP   4096 // bucket capacity; mean 2176

// Pass 1: bucket edges by dst>>7 into block-exclusive runs; zero gsum/gcnt.
__global__ __launch_bounds__(256)
void k_bucket(const int* __restrict__ ei, unsigned int* __restrict__ bkt,
              int* __restrict__ bcnt, float* __restrict__ gsum,
              int* __restrict__ gcnt, int Ne, int Nn, int nbkt, int Gg) {
    __shared__ int lcnt[MAXBKT];
    __shared__ int lbase[MAXBKT];
    int tid = threadIdx.x;
    int gid = blockIdx.x * 256 + tid;
    if (gid < Gg * 128) gsum[gid] = 0.f;
    if (gid < Gg) gcnt[gid] = 0;
    for (int i = tid; i < nbkt; i += 256) lcnt[i] = 0;
    __syncthreads();
    int chunk0 = blockIdx.x * 2048;
    int nnz = Ne + Nn;
    for (int i = 0; i < 8; ++i) {
        int e = chunk0 + i * 256 + tid;
        if (e < nnz) {
            int d = (e < Ne) ? ei[Ne + e] : (e - Ne);
            atomicAdd(&lcnt[d >> 7], 1);
        }
    }
    __syncthreads();
    for (int b = tid; b < nbkt; b += 256) {
        int c = lcnt[b];
        lbase[b] = (c > 0) ? atomicAdd(&bcnt[b], c) : 0;
        lcnt[b] = 0;
    }
    __syncthreads();
    for (int i = 0; i < 8; ++i) {
        int e = chunk0 + i * 256 + tid;
        if (e < nnz) {
            int s, d;
            if (e < Ne) { s = ei[e]; d = ei[Ne + e]; }
            else        { s = e - Ne; d = e - Ne; }
            int b = d >> 7;
            int r = atomicAdd(&lcnt[b], 1);
            bkt[(long)b * BCAP + lbase[b] + r] = ((unsigned)s << 7) | (unsigned)(d & 127);
        }
    }
}

// One-block exclusive scan of the nbkt bucket counts.
__global__ __launch_bounds__(1024)
void k_bktscan(const int* __restrict__ bcnt, int* __restrict__ bktbase, int nbkt) {
    __shared__ int s0[1024], s1[1024];
    int t = threadIdx.x;
    int v = (t < nbkt) ? bcnt[t] : 0;
    s0[t] = v;
    __syncthreads();
    int* src = s0; int* dst = s1;
    for (int off = 1; off < 1024; off <<= 1) {
        int x = src[t];
        if (t >= off) x += src[t - off];
        dst[t] = x;
        __syncthreads();
        int* tw = src; src = dst; dst = tw;
    }
    if (t < nbkt) bktbase[t] = src[t] - v;   // exclusive
}

// Per-bucket: LDS hist -> LDS scan -> coalesced rowptr write -> scatter col.
__global__ __launch_bounds__(256)
void k_bscatter2(const unsigned int* __restrict__ bkt, const int* __restrict__ bcnt,
                 const int* __restrict__ bktbase, int* __restrict__ rowptr,
                 int* __restrict__ colv, int Nn, int nnz) {
    __shared__ int h[128], sc0[128], sc1[128];
    int b = blockIdx.x;
    int tid = threadIdx.x;
    if (tid < 128) h[tid] = 0;
    __syncthreads();
    int cnt = bcnt[b];
    int base = bktbase[b];
    const unsigned int* bp = bkt + (long)b * BCAP;
    for (int i = tid; i < cnt; i += 256) atomicAdd(&h[bp[i] & 127], 1);
    __syncthreads();
    if (tid < 128) sc0[tid] = h[tid];
    __syncthreads();
    int* src = sc0; int* dst = sc1;
    for (int off = 1; off < 128; off <<= 1) {
        if (tid < 128) {
            int x = src[tid];
            if (tid >= off) x += src[tid - off];
            dst[tid] = x;
        }
        __syncthreads();
        int* tw = src; src = dst; dst = tw;
    }
    int node = b * 128 + tid;
    if (tid < 128) {
        int excl = src[tid] - h[tid];
        int st = base + excl;
        h[tid] = st;                       // reuse as cursor
        if (node < Nn) rowptr[node] = st;
    }
    if (b == 0 && tid == 0) rowptr[Nn] = nnz;
    __syncthreads();
    for (int i = tid; i < cnt; i += 256) {
        unsigned int e = bp[i];
        int pos = atomicAdd(&h[e & 127], 1);
        colv[pos] = (int)(e >> 7);
    }
}

// merged prep: BN fold; W transpose/split bf16 hi/lo [l][col][k] cols 0..127;
// wa = W·att -> cols 128..135; zero pad 136..143.
__global__ void k_prep(const float* __restrict__ gamma, const float* __restrict__ beta,
                       const float* __restrict__ mean, const float* __restrict__ var,
                       float* __restrict__ bn_mul, float* __restrict__ bn_add,
                       const float* __restrict__ W, const float* __restrict__ asrc,
                       const float* __restrict__ adst,
                       __bf16* __restrict__ Hi, __bf16* __restrict__ Lo) {
    int gid = blockIdx.x * 256 + threadIdx.x;
    if (gid < 384) {
        float sc = gamma[gid] / sqrtf(var[gid] + 1e-5f);
        bn_mul[gid] = sc;
        bn_add[gid] = beta[gid] - mean[gid] * sc;
    }
    if (gid < 3 * 128 * 128) {
        int l = gid >> 14;
        int k = (gid >> 7) & 127;
        int n = gid & 127;
        float f = W[gid];
        __bf16 h = (__bf16)f;
        int o = l * BSTRIDE + n * 128 + k;
        Hi[o] = h;
        Lo[o] = (__bf16)(f - (float)h);
    }
    if (gid < 3 * 128 * 8) {            // wa projections
        int l = gid >> 10;
        int r = gid & 1023;
        int k = r >> 3;
        int j = r & 7;                  // 0..3 src head, 4..7 dst head
        int hh = j & 3;
        const float* av = (j < 4 ? asrc : adst) + l * 128 + hh * 32;
        const float* wp = W + l * 16384 + k * 128 + hh * 32;
        float sum = 0.f;
#pragma unroll
        for (int d = 0; d < 32; ++d) sum = fmaf(wp[d], av[d], sum);
        __bf16 h = (__bf16)sum;
        int o = l * BSTRIDE + (128 + j) * 128 + k;
        Hi[o] = h;
        Lo[o] = (__bf16)(sum - (float)h);
    }
    if (gid < 3 * 128 * 8) {            // zero pad cols 136..143
        int l = gid >> 10;
        int r = gid & 1023;
        int k = r >> 3;
        int j = r & 7;
        int o = l * BSTRIDE + (136 + j) * 128 + k;
        Hi[o] = (__bf16)0.f;
        Lo[o] = (__bf16)0.f;
    }
}

// MFMA GEMM v3 over extended B (144 cols), operand-swapped (computes h^T
// fragments). Per K-slice (32), the W hi/lo slice (18 tiles of 1KB, frag
// order: tile (d,ct) at sB[tile*512 + lane*8]) is staged in LDS by all 4
// waves, then each wave reads frags via stride-1 ds_read_b128.
// Lane li owns row r=rowBase+rt*16+li; per ct holds cols 16ct+4b..+3.
__global__ __launch_bounds__(256)
void k_gemm_mfma(const float* __restrict__ X, const __bf16* __restrict__ BtHi,
                 const __bf16* __restrict__ BtLo, __half* __restrict__ Hout,
                 float* __restrict__ as_, float* __restrict__ ad_, int Nn) {
    __shared__ __bf16 sB[18 * 512];    // 18 KB
    int t = threadIdx.x;
    int w = t >> 6;
    int lane = t & 63;
    int li = lane & 15;
    int b  = lane >> 4;          // 0..3
    long rowBase = (long)blockIdx.x * 128 + w * 32;

    f32x4 acc[2][9];
#pragma unroll
    for (int rt = 0; rt < 2; ++rt)
#pragma unroll
        for (int ct = 0; ct < 9; ++ct) acc[rt][ct] = (f32x4){0.f, 0.f, 0.f, 0.f};

    long rA[2];
#pragma unroll
    for (int rt = 0; rt < 2; ++rt) {
        long r = rowBase + rt * 16 + li;
        rA[rt] = (r > Nn - 1) ? (Nn - 1) : r;
    }
    const __bf16* Bt[2] = {BtHi, BtLo};

    for (int ks = 0; ks < 4; ++ks) {
        if (ks) __syncthreads();         // all waves done reading prev slice
        // ---- stage: wave w stages tiles w, w+4, ... (frag order) ----
#pragma unroll
        for (int tile = w; tile < 18; tile += 4) {
            int d = (tile >= 9) ? 1 : 0;
            int ct = tile - d * 9;
            bf16x8 v = *(const bf16x8*)(Bt[d] + (ct * 16 + li) * 128 + ks * 32 + b * 8);
            *(bf16x8*)(sB + tile * 512 + lane * 8) = v;
        }
        __syncthreads();

        // ---- X fragments for this K-slice ----
        int k0 = ks * 32 + 8 * b;
        bf16x8 ahi[2], alo[2];
#pragma unroll
        for (int rt = 0; rt < 2; ++rt) {
            const float* xp = X + rA[rt] * 128 + k0;
            float4 f0 = *(const float4*)xp;
            float4 f1 = *(const float4*)(xp + 4);
            float af[8] = {f0.x, f0.y, f0.z, f0.w, f1.x, f1.y, f1.z, f1.w};
#pragma unroll
            for (int j = 0; j < 8; ++j) {
                __bf16 h = (__bf16)af[j];
                ahi[rt][j] = h;
                alo[rt][j] = (__bf16)(af[j] - (float)h);
            }
        }
        // ---- compute ----
#pragma unroll
        for (int ct = 0; ct < 9; ++ct) {
            bf16x8 bhi = *(const bf16x8*)(sB + ct * 512 + lane * 8);
            bf16x8 blo = *(const bf16x8*)(sB + (9 + ct) * 512 + lane * 8);
#pragma unroll
            for (int rt = 0; rt < 2; ++rt) {
                acc[rt][ct] = __builtin_amdgcn_mfma_f32_16x16x32_bf16(bhi, ahi[rt], acc[rt][ct], 0, 0, 0);
                acc[rt][ct] = __builtin_amdgcn_mfma_f32_16x16x32_bf16(bhi, alo[rt], acc[rt][ct], 0, 0, 0);
                acc[rt][ct] = __builtin_amdgcn_mfma_f32_16x16x32_bf16(blo, ahi[rt], acc[rt][ct], 0, 0, 0);
            }
        }
    }

    // ---- store h (fp16, 8B packed) + attention scores (float4) ----
#pragma unroll
    for (int rt = 0; rt < 2; ++rt) {
        long r = rowBase + rt * 16 + li;
        if (r < Nn) {
            __half* op = Hout + r * 128 + 4 * b;
#pragma unroll
            for (int ct = 0; ct < 8; ++ct) {
                union { __half2 h2[2]; uint2 u; } pk;
                pk.h2[0] = __floats2half2_rn(acc[rt][ct][0], acc[rt][ct][1]);
                pk.h2[1] = __floats2half2_rn(acc[rt][ct][2], acc[rt][ct][3]);
                *(uint2*)(op + ct * 16) = pk.u;
            }
            if (b == 0)
                *(float4*)(as_ + 4 * r) = make_float4(acc[rt][8][0], acc[rt][8][1],
                                                      acc[rt][8][2], acc[rt][8][3]);
            else if (b == 1)
                *(float4*)(ad_ + 4 * r) = make_float4(acc[rt][8][0], acc[rt][8][1],
                                                      acc[rt][8][2], acc[rt][8][3]);
        }
    }
}

#define LEAKY(x) ((x) > 0.f ? (x) : 0.2f * (x))

// One wave per dst node, 4 nodes/block. h rows are fp16 (256 B); lane li owns
// 8 cols = 16 B per edge; 8 edges/iter. fp32 accumulate.
__global__ __launch_bounds__(256)
void k_aggregate(const __half* __restrict__ Hb, const float* __restrict__ as_,
                 const float* __restrict__ ad_, const int* __restrict__ rowptr,
                 const int* __restrict__ col, const float* __restrict__ bias,
                 const float* __restrict__ bn_mul, const float* __restrict__ bn_add,
                 float* __restrict__ Xout, int Nn) {
    __shared__ float s_alpha[4][64][4];
    __shared__ int   s_off[4][64];
    int w = threadIdx.x >> 6;
    int n = (blockIdx.x << 2) + w;
    if (n >= Nn) return;
    int lane = threadIdx.x & 63;
    int start = rowptr[n], end = rowptr[n + 1];
    int deg = end - start;

    if (deg <= 64) {
        // ---- phase A: lane=(slot,head), one-shot softmax ----
        int hh = lane & 3;
        int slot = lane >> 2;
        float adn = ad_[4 * n + hh];
        float esc[4]; int scl[4];
#pragma unroll
        for (int c = 0; c < 4; ++c) {
            int eidx = (c << 4) + slot;
            float e = -1e30f; int s = 0;
            if (eidx < deg) {
                s = col[start + eidx];
                e = LEAKY(as_[4 * s + hh] + adn);
            }
            esc[c] = e; scl[c] = s;
        }
        float m = fmaxf(fmaxf(esc[0], esc[1]), fmaxf(esc[2], esc[3]));
#pragma unroll
        for (int msk = 4; msk < 64; msk <<= 1) m = fmaxf(m, __shfl_xor(m, msk, 64));
        float p[4];
        float den = 0.f;
#pragma unroll
        for (int c = 0; c < 4; ++c) { p[c] = __expf(esc[c] - m); den += p[c]; }
#pragma unroll
        for (int msk = 4; msk < 64; msk <<= 1) den += __shfl_xor(den, msk, 64);
        float inv = 1.f / (den + 1e-16f);
#pragma unroll
        for (int c = 0; c < 4; ++c)
            s_alpha[w][(c << 4) + slot][hh] = p[c] * inv;
        if (hh == 0) {
#pragma unroll
            for (int c = 0; c < 4; ++c)
                s_off[w][(c << 4) + slot] = scl[c] << 8;   // byte offset (fp16 row)
        }

        // ---- phase B: 8 edges per iter (2 x 4 quarters), 16B/lane ----
        int quarter = lane >> 4;
        int li = lane & 15;
        int hB = li >> 2;
        int cByte = li << 4;                 // 16 B = 8 halves
        const char* hb8 = (const char*)Hb;
        float accA[8], accB[8];
#pragma unroll
        for (int i = 0; i < 8; ++i) { accA[i] = 0.f; accB[i] = 0.f; }
        int degU = (deg + 7) & ~7;
        for (int j = 0; j < degU; j += 8) {
            int e0 = j + quarter;
            int e1 = j + 4 + quarter;
            int off0 = s_off[w][e0];
            int off1 = s_off[w][e1];
            float al0 = s_alpha[w][e0][hB];
            float al1 = s_alpha[w][e1][hB];
            u32x4 r0 = *(const u32x4*)(hb8 + off0 + cByte);
            u32x4 r1 = *(const u32x4*)(hb8 + off1 + cByte);
            const __half2* h0 = (const __half2*)&r0;
            const __half2* h1 = (const __half2*)&r1;
#pragma unroll
            for (int q = 0; q < 4; ++q) {
                float2 f0 = __half22float2(h0[q]);
                float2 f1 = __half22float2(h1[q]);
                accA[2 * q]     = fmaf(f0.x, al0, accA[2 * q]);
                accA[2 * q + 1] = fmaf(f0.y, al0, accA[2 * q + 1]);
                accB[2 * q]     = fmaf(f1.x, al1, accB[2 * q]);
                accB[2 * q + 1] = fmaf(f1.y, al1, accB[2 * q + 1]);
            }
        }
        float acc[8];
#pragma unroll
        for (int i = 0; i < 8; ++i) {
            float v = accA[i] + accB[i];
            v += __shfl_xor(v, 16, 64);
            v += __shfl_xor(v, 32, 64);
            acc[i] = v;
        }
        if (lane < 16) {
            int c0 = li << 3;
            float4 bz0 = *(const float4*)(bias + c0);
            float4 bz1 = *(const float4*)(bias + c0 + 4);
            float4 m0 = *(const float4*)(bn_mul + c0);
            float4 m1 = *(const float4*)(bn_mul + c0 + 4);
            float4 a0 = *(const float4*)(bn_add + c0);
            float4 a1 = *(const float4*)(bn_add + c0 + 4);
            float4 o0, o1;
            o0.x = fmaf(fmaxf(acc[0] + bz0.x, 0.f), m0.x, a0.x);
            o0.y = fmaf(fmaxf(acc[1] + bz0.y, 0.f), m0.y, a0.y);
            o0.z = fmaf(fmaxf(acc[2] + bz0.z, 0.f), m0.z, a0.z);
            o0.w = fmaf(fmaxf(acc[3] + bz0.w, 0.f), m0.w, a0.w);
            o1.x = fmaf(fmaxf(acc[4] + bz1.x, 0.f), m1.x, a1.x);
            o1.y = fmaf(fmaxf(acc[5] + bz1.y, 0.f), m1.y, a1.y);
            o1.z = fmaf(fmaxf(acc[6] + bz1.z, 0.f), m1.z, a1.z);
            o1.w = fmaf(fmaxf(acc[7] + bz1.w, 0.f), m1.w, a1.w);
            *(float4*)(Xout + (long)n * 128 + c0)     = o0;
            *(float4*)(Xout + (long)n * 128 + c0 + 4) = o1;
        }
        return;
    }

    // ---- fallback (deg > 64): 3-pass ----
    int hh = lane & 3;
    float adn = ad_[n * 4 + hh];
    float m = -1e30f;
    for (int base = start; base < end; base += 16) {
        int idx = base + (lane >> 2);
        float sc = -1e30f;
        if (idx < end) {
            int s = col[idx];
            float e = as_[s * 4 + hh] + adn;
            sc = LEAKY(e);
        }
        m = fmaxf(m, sc);
    }
    for (int msk = 4; msk < 64; msk <<= 1) m = fmaxf(m, __shfl_xor(m, msk, 64));
    float den = 0.f;
    for (int base = start; base < end; base += 16) {
        int idx = base + (lane >> 2);
        if (idx < end) {
            int s = col[idx];
            float e = as_[s * 4 + hh] + adn;
            e = LEAKY(e);
            den += __expf(e - m);
        }
    }
    for (int msk = 4; msk < 64; msk <<= 1) den += __shfl_xor(den, msk, 64);
    int hB = lane >> 4;
    float mB   = __shfl(m, hB, 64);
    float invB = 1.f / (__shfl(den, hB, 64) + 1e-16f);
    float adB  = ad_[n * 4 + hB];
    int c0 = lane << 1;
    float acc0 = 0.f, acc1 = 0.f;
    for (int i = start; i < end; ++i) {
        int s = col[i];
        float e = as_[s * 4 + hB] + adB;
        e = LEAKY(e);
        float alpha = __expf(e - mB) * invB;
        float2 hv = __half22float2(*(const __half2*)(Hb + (long)s * 128 + c0));
        acc0 = fmaf(hv.x, alpha, acc0);
        acc1 = fmaf(hv.y, alpha, acc1);
    }
    float v0 = acc0 + bias[c0], v1 = acc1 + bias[c0 + 1];
    v0 = fmaxf(v0, 0.f); v1 = fmaxf(v1, 0.f);
    v0 = fmaf(v0, bn_mul[c0], bn_add[c0]);
    v1 = fmaf(v1, bn_mul[c0 + 1], bn_add[c0 + 1]);
    *(float2*)(Xout + (long)n * 128 + c0) = make_float2(v0, v1);
}

__global__ __launch_bounds__(128)
void k_pool(const float* __restrict__ X, const int* __restrict__ batch,
            float* __restrict__ gsum, int* __restrict__ gcnt, int Nn) {
    int c = threadIdx.x;
    int n0 = blockIdx.x * 64;
    if (n0 >= Nn) return;
    int nend = (n0 + 64 < Nn) ? n0 + 64 : Nn;
    float local = 0.f;
    int gcur = batch[n0];
    int cnt = 0;
    for (int n = n0; n < nend; ++n) {
        int g = batch[n];
        if (g != gcur) {
            atomicAdd(&gsum[gcur * 128 + c], local);
            if (c == 0) atomicAdd(&gcnt[gcur], cnt);
            local = 0.f; cnt = 0; gcur = g;
        }
        local += X[(long)n * 128 + c];
        cnt += 1;
    }
    atomicAdd(&gsum[gcur * 128 + c], local);
    if (c == 0) atomicAdd(&gcnt[gcur], cnt);
}

__global__ __launch_bounds__(64)
void k_head(const float* __restrict__ gsum, const int* __restrict__ gcnt,
            const float* __restrict__ Wh1, const float* __restrict__ bh1,
            const float* __restrict__ Wh2, const float* __restrict__ bh2,
            float* __restrict__ outp) {
    __shared__ float pooled[128];
    int g = blockIdx.x;
    int j = threadIdx.x;
    int cnt = gcnt[g];
    float inv = 1.f / (float)(cnt > 1 ? cnt : 1);
    pooled[j]      = gsum[g * 128 + j] * inv;
    pooled[j + 64] = gsum[g * 128 + 64 + j] * inv;
    __syncthreads();
    float acc = bh1[j];
    for (int k = 0; k < 128; ++k) acc = fmaf(pooled[k], Wh1[k * 64 + j], acc);
    acc = fmaxf(acc, 0.f);
    float prod = acc * Wh2[j];
    for (int msk = 1; msk < 64; msk <<= 1) prod += __shfl_xor(prod, msk, 64);
    if (j == 0) outp[g] = prod + bh2[0];
}

extern "C" void kernel_launch(void* const* d_in, const int* in_sizes, int n_in,
                              void* d_out, int out_size, void* d_ws, size_t ws_size,
                              hipStream_t stream) {
    const float* x       = (const float*)d_in[0];
    const int*   ei      = (const int*)d_in[1];
    const int*   batch   = (const int*)d_in[2];
    const float* W       = (const float*)d_in[3];
    const float* att_src = (const float*)d_in[4];
    const float* att_dst = (const float*)d_in[5];
    const float* bias    = (const float*)d_in[6];
    const float* gamma   = (const float*)d_in[7];
    const float* beta    = (const float*)d_in[8];
    const float* bn_mean = (const float*)d_in[9];
    const float* bn_var  = (const float*)d_in[10];
    const float* Wh1     = (const float*)d_in[11];
    const float* bh1     = (const float*)d_in[12];
    const float* Wh2     = (const float*)d_in[13];
    const float* bh2     = (const float*)d_in[14];
    float* out = (float*)d_out;

    const int Nn = in_sizes[0] / 128;
    const int Ne = in_sizes[1] / 2;
    const int Gg = out_size;
    const int nnz = Ne + Nn;
    const int nbkt = (Nn + 127) / 128;

    char* ws = (char*)d_ws;
    size_t off = 0;
    auto alloc = [&](size_t bytes) -> char* {
        char* p = ws + off;
        off = (off + bytes + 255) & ~(size_t)255;
        return p;
    };
    float*        bufA    = (float*)alloc((size_t)Nn * 128 * 4);
    __half*       bufH    = (__half*)alloc((size_t)Nn * 128 * 2);
    float*        as_     = (float*)alloc((size_t)Nn * 4 * 4);
    float*        ad_     = (float*)alloc((size_t)Nn * 4 * 4);
    int*          rowptr  = (int*)alloc((size_t)(Nn + 1) * 4);
    int*          col     = (int*)alloc((size_t)nnz * 4);
    float*        bn_mul  = (float*)alloc(384 * 4);
    float*        bn_add  = (float*)alloc(384 * 4);
    float*        gsum    = (float*)alloc((size_t)Gg * 128 * 4);
    int*          gcnt    = (int*)alloc((size_t)Gg * 4);
    __bf16*       WtHi    = (__bf16*)alloc((size_t)3 * BSTRIDE * 2);
    __bf16*       WtLo    = (__bf16*)alloc((size_t)3 * BSTRIDE * 2);
    unsigned int* bkt     = (unsigned int*)alloc((size_t)nbkt * BCAP * 4);
    int*          bcnt    = (int*)alloc((size_t)nbkt * 4);
    int*          bktbase = (int*)alloc((size_t)nbkt * 4);

    // ---- CSR build (consolidated) + param prep ----
    hipMemsetAsync(bcnt, 0, (size_t)nbkt * 4, stream);
    k_prep<<<192, 256, 0, stream>>>(gamma, beta, bn_mean, bn_var, bn_mul, bn_add,
                                    W, att_src, att_dst, WtHi, WtLo);
    k_bucket<<<(nnz + 2047) / 2048, 256, 0, stream>>>(ei, bkt, bcnt, gsum, gcnt,
                                                      Ne, Nn, nbkt, Gg);
    k_bktscan<<<1, 1024, 0, stream>>>(bcnt, bktbase, nbkt);
    k_bscatter2<<<nbkt, 256, 0, stream>>>(bkt, bcnt, bktbase, rowptr, col, Nn, nnz);

    // ---- 3 GAT layers ----
    const float* cur = x;
    for (int l = 0; l < 3; ++l) {
        k_gemm_mfma<<<(Nn + 127) / 128, 256, 0, stream>>>(cur, WtHi + l * BSTRIDE,
                                                          WtLo + l * BSTRIDE,
                                                          bufH, as_, ad_, Nn);
        k_aggregate<<<(Nn + 3) / 4, 256, 0, stream>>>(bufH, as_, ad_, rowptr, col,
                                                      bias + l * 128, bn_mul + l * 128,
                                                      bn_add + l * 128, bufA, Nn);
        cur = bufA;
    }

    // ---- pool + head ----
    k_pool<<<(Nn + 63) / 64, 128, 0, stream>>>(bufA, batch, gsum, gcnt, Nn);
    k_head<<<Gg, 64, 0, stream>>>(gsum, gcnt, Wh1, bh1, Wh2, bh2, out);
}